// Round 4
// baseline (205.743 us; speedup 1.0000x reference)
//
#include <hip/hip_runtime.h>

#define H_ 1024
#define NH_ 16
#define HD_ 64
#define B_ 2
#define S_ 2048
#define BS_ 4096

typedef _Float16 half8 __attribute__((ext_vector_type(8)));
typedef _Float16 half4_t __attribute__((ext_vector_type(4)));
typedef __fp16 fp16x2 __attribute__((ext_vector_type(2)));
typedef __fp16 fp16x4 __attribute__((ext_vector_type(4)));
typedef float floatx4 __attribute__((ext_vector_type(4)));

#define LOG2E 1.44269504088896f

__device__ __forceinline__ void async_copy16(void* lds, const void* g) {
  __builtin_amdgcn_global_load_lds(
      (const __attribute__((address_space(1))) unsigned int*)g,
      (__attribute__((address_space(3))) unsigned int*)lds, 16, 0, 0);
}

__device__ __forceinline__ half4_t pack4(float a, float b, float c, float d) {
  fp16x2 lo = __builtin_amdgcn_cvt_pkrtz(a, b);
  fp16x2 hi = __builtin_amdgcn_cvt_pkrtz(c, d);
  fp16x4 r = __builtin_shufflevector(lo, hi, 0, 1, 2, 3);
  return __builtin_bit_cast(half4_t, r);
}

// ---------------- fp32 -> fp16 conversion (hs + 4 weights) ----------------
__global__ __launch_bounds__(256) void cvt_all(
    const float* __restrict__ hs, const float* __restrict__ wq,
    const float* __restrict__ wk, const float* __restrict__ wv,
    const float* __restrict__ wo,
    _Float16* __restrict__ hs_h, _Float16* __restrict__ w_h) {
  int i = blockIdx.x * 256 + threadIdx.x;
  int idx = i * 4;
  const float* src; _Float16* dst; int off;
  if (idx < BS_ * H_) {
    src = hs; dst = hs_h; off = idx;
  } else {
    int j = idx - BS_ * H_;
    int w = j >> 20;
    off = j & ((1 << 20) - 1);
    src = (w == 0) ? wq : (w == 1) ? wk : (w == 2) ? wv : wo;
    dst = w_h + (size_t)w * (H_ * H_);
  }
  float4 f = *(const float4*)(src + off);
  half4_t o;
  o.x = (_Float16)f.x; o.y = (_Float16)f.y;
  o.z = (_Float16)f.z; o.w = (_Float16)f.w;
  *(half4_t*)(dst + off) = o;
}

// ---------------- Fused QKV GEMM: C = A @ [Wq;Wk;Wv]^T ---------------------
// grid (12, 16) block 512 (8 waves 2Mx4N). BM=BN=256, BK=32.
// Ring-4 K-tile LDS buffers (128 KB), stage-ahead 3, counted vmcnt(8)
// (never 0 in main loop) + raw s_barrier -> loads stay in flight across
// barriers (T4). LDS XOR-swizzle slot^=(row>>1)&3: conflict-free
// ds_read_b128 (staged via pre-swizzled global source, m173 pattern).
// Stage target (t+3)&3 == buffer computed in iter t-1, readers fenced by
// iter t's barrier -> deterministic, no read/write aliasing.
__global__ __launch_bounds__(512, 2) void qkv_fused(
    const _Float16* __restrict__ A, const _Float16* __restrict__ Wall,
    _Float16* __restrict__ qh, _Float16* __restrict__ kh,
    _Float16* __restrict__ vt) {
  const int rbase = blockIdx.y * 256;
  const int cbase = blockIdx.x * 256;
  const int z = cbase >> 10;  // 0=q 1=k 2=v (uniform per block)
  __shared__ _Float16 Ab[4][256 * 32];
  __shared__ _Float16 Bb[4][256 * 32];
  const int tid = threadIdx.x, lane = tid & 63, w = tid >> 6;
  const int quad = lane >> 4, l16 = lane & 15;
  const int wm = w >> 2, wn = w & 3;

  floatx4 zero = {0.f, 0.f, 0.f, 0.f};
  floatx4 acc[8][4];
#pragma unroll
  for (int m = 0; m < 8; ++m)
#pragma unroll
    for (int n = 0; n < 4; ++n) acc[m][n] = zero;

  // staging: per thread 2 A-copies + 2 B-copies per K-tile.
  // LDS dest is linear in tid (base + lane*16) as global_load_lds requires;
  // source col-slot is pre-swizzled so reads can use slot^((row>>1)&3).
  const int srow = tid >> 2;          // + u*128
  const int pslot = tid & 3;
  const int sslot = pslot ^ ((tid >> 3) & 3);  // == pslot ^ ((srow>>1)&3)
  const _Float16* Ag = A + (size_t)(rbase + srow) * H_ + sslot * 8;
  const _Float16* Bg = Wall + (size_t)(cbase + srow) * H_ + sslot * 8;

  auto STAGE = [&](int t) {
    const int k0 = t * 32;
    _Float16* ab = &Ab[t & 3][0];
    _Float16* bb = &Bb[t & 3][0];
#pragma unroll
    for (int u = 0; u < 2; ++u)
      async_copy16(ab + (size_t)(u * 128 + srow) * 32 + pslot * 8,
                   Ag + (size_t)u * 128 * H_ + k0);
#pragma unroll
    for (int u = 0; u < 2; ++u)
      async_copy16(bb + (size_t)(u * 128 + srow) * 32 + pslot * 8,
                   Bg + (size_t)u * 128 * H_ + k0);
  };

  const int rsw = (l16 >> 1) & 3;  // fragment row>>1 & 3 (base bits are 0)
  auto COMPUTE = [&](int t) {
    const _Float16* Ap = &Ab[t & 3][0];
    const _Float16* Bp = &Bb[t & 3][0];
    half8 af[8], bf[4];
#pragma unroll
    for (int m = 0; m < 8; ++m) {
      int row = wm * 128 + m * 16 + l16;
      af[m] = *(const half8*)&Ap[row * 32 + ((quad ^ rsw) * 8)];
    }
#pragma unroll
    for (int n = 0; n < 4; ++n) {
      int row = wn * 64 + n * 16 + l16;
      bf[n] = *(const half8*)&Bp[row * 32 + ((quad ^ rsw) * 8)];
    }
    __builtin_amdgcn_s_setprio(1);
#pragma unroll
    for (int m = 0; m < 8; ++m)
#pragma unroll
      for (int n = 0; n < 4; ++n)
        acc[m][n] = __builtin_amdgcn_mfma_f32_16x16x32_f16(af[m], bf[n],
                                                           acc[m][n], 0, 0, 0);
    __builtin_amdgcn_s_setprio(0);
  };

  // prologue: 3 K-tiles in flight (12 loads/thread)
  STAGE(0); STAGE(1); STAGE(2);

  // main loop: NT=32 K-tiles. vmcnt(8) = 2 K-tiles (8 loads) stay in flight.
  for (int t = 0; t < 30; ++t) {
    asm volatile("s_waitcnt vmcnt(8)" ::: "memory");
    __builtin_amdgcn_sched_barrier(0);
    __builtin_amdgcn_s_barrier();
    __builtin_amdgcn_sched_barrier(0);
    if (t < 29) STAGE(t + 3);
    COMPUTE(t);
  }
  asm volatile("s_waitcnt vmcnt(4)" ::: "memory");
  __builtin_amdgcn_sched_barrier(0);
  __builtin_amdgcn_s_barrier();
  __builtin_amdgcn_sched_barrier(0);
  COMPUTE(30);
  asm volatile("s_waitcnt vmcnt(0)" ::: "memory");
  __builtin_amdgcn_sched_barrier(0);
  __builtin_amdgcn_s_barrier();
  __builtin_amdgcn_sched_barrier(0);
  COMPUTE(31);

  // epilogue: z-dependent activation / layout
#pragma unroll
  for (int m = 0; m < 8; ++m) {
    int r0 = rbase + wm * 128 + m * 16 + quad * 4;
    int b = r0 >> 11, sl0 = r0 & (S_ - 1);
#pragma unroll
    for (int n = 0; n < 4; ++n) {
      int col = cbase + wn * 64 + n * 16 + l16;
      int c = col & 1023;
      int h = c >> 6, d = c & 63;
      if (z == 2) {
        half4_t pk = pack4(acc[m][n][0], acc[m][n][1], acc[m][n][2],
                           acc[m][n][3]);
        *(half4_t*)&vt[((size_t)(b * NH_ + h) * HD_ + d) * S_ + sl0] = pk;
      } else {
        _Float16* outp = (z == 0) ? qh : kh;
        float scale = (z == 0) ? LOG2E : 1.0f;
#pragma unroll
        for (int r = 0; r < 4; ++r) {
          float x = acc[m][n][r];
          x = ((x > 0.f) ? (x + 1.f) : __expf(x)) * scale;
          outp[((size_t)(b * NH_ + h) * S_ + sl0 + r) * HD_ + d] = (_Float16)x;
        }
      }
    }
  }
}

// ---------------- Flash attention ------------------------------------------
// grid (S/128=16, B*NH=32) block 256 (4 waves, 32 q-rows each), BC=128.
// Swapped-operand scheme: QK computes S^T (mfma A=K,B=Q); P^T feeds PV
// directly from registers via 16x16x16 MFMA (no P LDS round-trip).
// K/V double-buffered via global_load_lds; ONE barrier per tile.
__global__ __launch_bounds__(256, 2) void flash_attn(
    const _Float16* __restrict__ qh, const _Float16* __restrict__ kh,
    const _Float16* __restrict__ vt, const int* __restrict__ mask,
    _Float16* __restrict__ attn_out) {
  const int bh = blockIdx.y, b = bh >> 4, h = bh & 15;
  const int qbase = blockIdx.x * 128;
  const int tid = threadIdx.x, w = tid >> 6, lane = tid & 63;
  const int quad = lane >> 4, l16 = lane & 15;

  __shared__ _Float16 Kt[2][128 * 64];  // [key][d], slot = (d>>3)^(key&7)
  __shared__ _Float16 Vt[2][64 * 128];  // [d][key], slot = (key>>3)^(d&15)

  const _Float16* Q = qh + (size_t)bh * (S_ * HD_);
  const _Float16* K = kh + (size_t)bh * (S_ * HD_);
  const _Float16* Vg = vt + (size_t)bh * (HD_ * S_);
  const int* Mb = mask + b * S_;

  // Q B-fragments (2 row-groups of 16 q) in registers for the whole kernel
  half8 qf[2][2];
#pragma unroll
  for (int g = 0; g < 2; ++g) {
    int qr = qbase + w * 32 + g * 16 + l16;
    qf[g][0] = *(const half8*)&Q[qr * 64 + quad * 8];
    qf[g][1] = *(const half8*)&Q[qr * 64 + 32 + quad * 8];
  }

  floatx4 zero = {0.f, 0.f, 0.f, 0.f};
  floatx4 o[2][4];  // O^T[d = ct2*16 + quad*4 + r][q = l16 (group g)]
#pragma unroll
  for (int g = 0; g < 2; ++g)
#pragma unroll
    for (int i = 0; i < 4; ++i) o[g][i] = zero;
  float mi[2] = {-3e38f, -3e38f}, li[2] = {0.f, 0.f};

  // staging constants
  const int krow_off = lane >> 3;             // 0..7
  const int kslot = lane & 7;
  const int kchunk = kslot ^ (krow_off & 7);
  const int vrow_off = lane >> 4;             // 0..3
  const int vslot = lane & 15;

  // prologue: stage tile 0 into buffer 0
  {
#pragma unroll
    for (int u = 0; u < 4; ++u) {
      int kl = w * 32 + u * 8;
      async_copy16(&Kt[0][kl * 64], K + (size_t)(kl + krow_off) * 64 + kchunk * 8);
    }
#pragma unroll
    for (int u = 0; u < 4; ++u) {
      int d0 = w * 16 + u * 4 + vrow_off;
      int c0 = vslot ^ (d0 & 15);
      async_copy16(&Vt[0][(w * 16 + u * 4) * 128], Vg + (size_t)d0 * S_ + c0 * 8);
    }
  }

  for (int kt = 0; kt < S_ / 128; ++kt) {
    const int key0 = kt * 128;
    const int buf = kt & 1;
    // barrier: compiler-inserted vmcnt(0) drains our DMA (issued a full tile
    // ago -> latency hidden); barrier makes all waves' DMA visible.
    __syncthreads();
    // prefetch next tile into the other buffer
    if (kt < S_ / 128 - 1) {
      const int key1 = key0 + 128;
#pragma unroll
      for (int u = 0; u < 4; ++u) {
        int kl = w * 32 + u * 8;
        async_copy16(&Kt[buf ^ 1][kl * 64],
                     K + (size_t)(key1 + kl + krow_off) * 64 + kchunk * 8);
      }
#pragma unroll
      for (int u = 0; u < 4; ++u) {
        int d0 = w * 16 + u * 4 + vrow_off;
        int c0 = vslot ^ (d0 & 15);
        async_copy16(&Vt[buf ^ 1][(w * 16 + u * 4) * 128],
                     Vg + (size_t)d0 * S_ + key1 + c0 * 8);
      }
    }
    int m0 = Mb[key0 + lane];
    int m1 = Mb[key0 + 64 + lane];

    const _Float16* Kb = &Kt[buf][0];
    const _Float16* Vb = &Vt[buf][0];

    // S^T tile: mfma(A=K-frag, B=Q-frag) -> S^T[key=ct*16+quad*4+r][q=l16]
    floatx4 sa[2][8];
#pragma unroll
    for (int g = 0; g < 2; ++g)
#pragma unroll
      for (int ct = 0; ct < 8; ++ct) sa[g][ct] = zero;
    {
      int s0 = quad ^ (l16 & 7);
      int s1 = (4 + quad) ^ (l16 & 7);
#pragma unroll
      for (int ct = 0; ct < 8; ++ct) {
        int key = ct * 16 + l16;
        half8 bf0 = *(half8*)&Kb[key * 64 + s0 * 8];
        half8 bf1 = *(half8*)&Kb[key * 64 + s1 * 8];
        sa[0][ct] = __builtin_amdgcn_mfma_f32_16x16x32_f16(bf0, qf[0][0], sa[0][ct], 0, 0, 0);
        sa[0][ct] = __builtin_amdgcn_mfma_f32_16x16x32_f16(bf1, qf[0][1], sa[0][ct], 0, 0, 0);
        sa[1][ct] = __builtin_amdgcn_mfma_f32_16x16x32_f16(bf0, qf[1][0], sa[1][ct], 0, 0, 0);
        sa[1][ct] = __builtin_amdgcn_mfma_f32_16x16x32_f16(bf1, qf[1][1], sa[1][ct], 0, 0, 0);
      }
    }
    // masking (fast path: tile fully unmasked). key = ct*16 + quad*4 + r
    if (__any((m0 == 0) || (m1 == 0))) {
#pragma unroll
      for (int ct = 0; ct < 8; ++ct)
#pragma unroll
        for (int r = 0; r < 4; ++r)
          if (Mb[key0 + ct * 16 + quad * 4 + r] == 0) {
            sa[0][ct][r] = -1e30f;
            sa[1][ct][r] = -1e30f;
          }
    }
    // online softmax per q-column (in-lane over 32 logits + 2 shuffles)
#pragma unroll
    for (int g = 0; g < 2; ++g) {
      float mx = sa[g][0][0];
#pragma unroll
      for (int ct = 0; ct < 8; ++ct)
#pragma unroll
        for (int r = 0; r < 4; ++r) mx = fmaxf(mx, sa[g][ct][r]);
      mx = fmaxf(mx, __shfl_xor(mx, 16));
      mx = fmaxf(mx, __shfl_xor(mx, 32));
      float mn = fmaxf(mi[g], mx);
      float alpha = __builtin_amdgcn_exp2f(mi[g] - mn);
      mi[g] = mn;
      float rs = 0.f;
#pragma unroll
      for (int ct = 0; ct < 8; ++ct)
#pragma unroll
        for (int r = 0; r < 4; ++r) {
          float p = __builtin_amdgcn_exp2f(sa[g][ct][r] - mn);
          sa[g][ct][r] = p;
          rs += p;
        }
      rs += __shfl_xor(rs, 16);
      rs += __shfl_xor(rs, 32);
      li[g] = li[g] * alpha + rs;
#pragma unroll
      for (int ct2 = 0; ct2 < 4; ++ct2) {
        o[g][ct2][0] *= alpha; o[g][ct2][1] *= alpha;
        o[g][ct2][2] *= alpha; o[g][ct2][3] *= alpha;
      }
    }
    // PV: O^T += mfma(A=V^T-frag, B=P^T-frag) over 8 key-chunks of 16.
    // P^T C-layout (key=quad*4+r) IS the 16x16x16 B-operand layout.
#pragma unroll
    for (int ct = 0; ct < 8; ++ct) {
      half4_t p0, p1;
#pragma unroll
      for (int r = 0; r < 4; ++r) {
        p0[r] = (_Float16)sa[0][ct][r];
        p1[r] = (_Float16)sa[1][ct][r];
      }
      int chunk = (2 * ct + (quad >> 1)) ^ l16;  // key-chunk swizzled by d&15
      int off = chunk * 8 + (quad & 1) * 4;
#pragma unroll
      for (int ct2 = 0; ct2 < 4; ++ct2) {
        int d = ct2 * 16 + l16;
        half4_t vf = *(half4_t*)&Vb[d * 128 + off];
        o[0][ct2] = __builtin_amdgcn_mfma_f32_16x16x16f16(vf, p0, o[0][ct2], 0, 0, 0);
        o[1][ct2] = __builtin_amdgcn_mfma_f32_16x16x16f16(vf, p1, o[1][ct2], 0, 0, 0);
      }
    }
  }
  // epilogue: normalize, store (B, S, H) fp16 — half4 stores (d contiguous)
#pragma unroll
  for (int g = 0; g < 2; ++g) {
    float inv = 1.0f / li[g];
    int row = qbase + w * 32 + g * 16 + l16;
#pragma unroll
    for (int ct2 = 0; ct2 < 4; ++ct2) {
      half4_t pk;
#pragma unroll
      for (int r = 0; r < 4; ++r) pk[r] = (_Float16)(o[g][ct2][r] * inv);
      int d = ct2 * 16 + quad * 4;
      *(half4_t*)&attn_out[((size_t)(b * S_ + row)) * H_ + h * HD_ + d] = pk;
    }
  }
}

// ---------------- Output GEMM: out = AO @ Wo^T (fp32 out) ------------------
// grid (16, 32) block 256: 128x64 tiles -> 512 blocks (2/CU)
__global__ __launch_bounds__(256) void out_gemm(
    const _Float16* __restrict__ A, const _Float16* __restrict__ W,
    float* __restrict__ out) {
  const int rbase = blockIdx.y * 128;
  const int cbase = blockIdx.x * 64;
  __shared__ _Float16 As[128 * 32];
  __shared__ _Float16 Bs[64 * 32];
  const int tid = threadIdx.x, lane = tid & 63, w = tid >> 6;
  const int quad = lane >> 4, l16 = lane & 15;

  floatx4 zero = {0.f, 0.f, 0.f, 0.f};
  floatx4 acc[2][4];
#pragma unroll
  for (int i = 0; i < 2; ++i)
#pragma unroll
    for (int j = 0; j < 4; ++j) acc[i][j] = zero;

  const int srowA = w * 32 + (lane >> 2);
  const int srowB = w * 16 + (lane >> 2);
  const int sseg = (lane & 3) * 8;
  const _Float16* Ag = A + (size_t)(rbase + srowA) * H_ + sseg;
  const _Float16* Bg = W + (size_t)(cbase + srowB) * H_ + sseg;

  for (int k0 = 0; k0 < H_; k0 += 32) {
    async_copy16(&As[(w * 32) * 32], Ag + k0);
    async_copy16(&As[(w * 32 + 16) * 32], Ag + 16 * H_ + k0);
    async_copy16(&Bs[(w * 16) * 32], Bg + k0);
    __syncthreads();
    half8 af[2], bf[4];
#pragma unroll
    for (int t = 0; t < 2; ++t)
      af[t] = *(half8*)&As[(w * 32 + t * 16 + l16) * 32 + quad * 8];
#pragma unroll
    for (int t = 0; t < 4; ++t)
      bf[t] = *(half8*)&Bs[(t * 16 + l16) * 32 + quad * 8];
#pragma unroll
    for (int i = 0; i < 2; ++i)
#pragma unroll
      for (int j = 0; j < 4; ++j)
        acc[i][j] = __builtin_amdgcn_mfma_f32_16x16x32_f16(af[i], bf[j],
                                                           acc[i][j], 0, 0, 0);
    __syncthreads();
  }
#pragma unroll
  for (int i = 0; i < 2; ++i) {
    int r0 = rbase + w * 32 + i * 16 + quad * 4;
#pragma unroll
    for (int j = 0; j < 4; ++j) {
      int col = cbase + j * 16 + l16;
#pragma unroll
      for (int r = 0; r < 4; ++r)
        out[(size_t)(r0 + r) * H_ + col] = acc[i][j][r];
    }
  }
}

extern "C" void kernel_launch(void* const* d_in, const int* in_sizes, int n_in,
                              void* d_out, int out_size, void* d_ws,
                              size_t ws_size, hipStream_t stream) {
  const float* hs = (const float*)d_in[0];
  const int* mask = (const int*)d_in[1];
  const float* Wq = (const float*)d_in[2];
  const float* Wk = (const float*)d_in[3];
  const float* Wv = (const float*)d_in[4];
  const float* Wo = (const float*)d_in[5];
  float* out = (float*)d_out;

  _Float16* p = (_Float16*)d_ws;
  _Float16* hs_h = p; p += (size_t)BS_ * H_;
  _Float16* w_h = p;  p += (size_t)4 * H_ * H_;
  _Float16* q_h = p;  p += (size_t)BS_ * H_;
  _Float16* k_h = p;  p += (size_t)BS_ * H_;
  _Float16* v_t = p;  p += (size_t)BS_ * H_;
  _Float16* ao_h = p; p += (size_t)BS_ * H_;

  cvt_all<<<8192, 256, 0, stream>>>(hs, Wq, Wk, Wv, Wo, hs_h, w_h);
  qkv_fused<<<dim3(12, 16), 512, 0, stream>>>(hs_h, w_h, q_h, k_h, v_t);
  flash_attn<<<dim3(16, 32), 256, 0, stream>>>(q_h, k_h, v_t, mask, ao_h);
  out_gemm<<<dim3(16, 32), 256, 0, stream>>>(ao_h, w_h + (size_t)3 * H_ * H_, out);
}

// Round 5
// 198.407 us; speedup vs baseline: 1.0370x; 1.0370x over previous
//
#include <hip/hip_runtime.h>

#define H_ 1024
#define NH_ 16
#define HD_ 64
#define B_ 2
#define S_ 2048
#define BS_ 4096

typedef _Float16 half8 __attribute__((ext_vector_type(8)));
typedef _Float16 half4_t __attribute__((ext_vector_type(4)));
typedef float floatx4 __attribute__((ext_vector_type(4)));

#define LOG2E 1.44269504088896f

__device__ __forceinline__ void async_copy16(void* lds, const void* g) {
  __builtin_amdgcn_global_load_lds(
      (const __attribute__((address_space(1))) unsigned int*)g,
      (__attribute__((address_space(3))) unsigned int*)lds, 16, 0, 0);
}

// ---------------- fp32 -> fp16 conversion (hs + 4 weights) ----------------
__global__ __launch_bounds__(256) void cvt_all(
    const float* __restrict__ hs, const float* __restrict__ wq,
    const float* __restrict__ wk, const float* __restrict__ wv,
    const float* __restrict__ wo,
    _Float16* __restrict__ hs_h, _Float16* __restrict__ w_h) {
  int i = blockIdx.x * 256 + threadIdx.x;
  int idx = i * 4;
  const float* src; _Float16* dst; int off;
  if (idx < BS_ * H_) {
    src = hs; dst = hs_h; off = idx;
  } else {
    int j = idx - BS_ * H_;
    int w = j >> 20;
    off = j & ((1 << 20) - 1);
    src = (w == 0) ? wq : (w == 1) ? wk : (w == 2) ? wv : wo;
    dst = w_h + (size_t)w * (H_ * H_);
  }
  float4 f = *(const float4*)(src + off);
  half4_t o;
  o.x = (_Float16)f.x; o.y = (_Float16)f.y;
  o.z = (_Float16)f.z; o.w = (_Float16)f.w;
  *(half4_t*)(dst + off) = o;
}

// ---------------- QKV GEMM: C = A @ W^T ------------------------------------
// grid (8, 32, 3) block 256. z: 0=q (elu+1, *log2e) 1=k (elu+1) 2=v (-> v^T)
__global__ __launch_bounds__(256) void qkv_gemm(
    const _Float16* __restrict__ A, const _Float16* __restrict__ Wall,
    _Float16* __restrict__ qh, _Float16* __restrict__ kh,
    _Float16* __restrict__ vt) {
  const int z = blockIdx.z;
  const _Float16* W = Wall + (size_t)z * (H_ * H_);
  const int rbase = blockIdx.y * 128;
  const int cbase = blockIdx.x * 128;
  __shared__ _Float16 As[128 * 32];
  __shared__ _Float16 Bs[128 * 32];
  const int tid = threadIdx.x, lane = tid & 63, w = tid >> 6;
  const int quad = lane >> 4, l16 = lane & 15;
  const int wr = (w >> 1) * 64, wc = (w & 1) * 64;

  floatx4 zero = {0.f, 0.f, 0.f, 0.f};
  floatx4 acc[4][4];
#pragma unroll
  for (int i = 0; i < 4; ++i)
#pragma unroll
    for (int j = 0; j < 4; ++j) acc[i][j] = zero;

  const int srow = w * 32 + (lane >> 2);
  const int sseg = (lane & 3) * 8;
  const _Float16* Ag = A + (size_t)(rbase + srow) * H_ + sseg;
  const _Float16* Bg = W + (size_t)(cbase + srow) * H_ + sseg;

  for (int k0 = 0; k0 < H_; k0 += 32) {
    async_copy16(&As[(w * 32) * 32], Ag + k0);
    async_copy16(&As[(w * 32 + 16) * 32], Ag + 16 * H_ + k0);
    async_copy16(&Bs[(w * 32) * 32], Bg + k0);
    async_copy16(&Bs[(w * 32 + 16) * 32], Bg + 16 * H_ + k0);
    __syncthreads();
    half8 af[4], bf[4];
#pragma unroll
    for (int t = 0; t < 4; ++t)
      af[t] = *(half8*)&As[(wr + t * 16 + l16) * 32 + quad * 8];
#pragma unroll
    for (int t = 0; t < 4; ++t)
      bf[t] = *(half8*)&Bs[(wc + t * 16 + l16) * 32 + quad * 8];
#pragma unroll
    for (int i = 0; i < 4; ++i)
#pragma unroll
      for (int j = 0; j < 4; ++j)
        acc[i][j] = __builtin_amdgcn_mfma_f32_16x16x32_f16(af[i], bf[j],
                                                           acc[i][j], 0, 0, 0);
    __syncthreads();
  }
  // epilogue
#pragma unroll
  for (int i = 0; i < 4; ++i) {
    int r0 = rbase + wr + i * 16 + quad * 4;
    int b = r0 >> 11, sl0 = r0 & (S_ - 1);
#pragma unroll
    for (int j = 0; j < 4; ++j) {
      int col = cbase + wc + j * 16 + l16;
      int h = col >> 6, d = col & 63;
      if (z == 2) {
        half4_t pk;
#pragma unroll
        for (int r = 0; r < 4; ++r) pk[r] = (_Float16)acc[i][j][r];
        *(half4_t*)&vt[((size_t)(b * NH_ + h) * HD_ + d) * S_ + sl0] = pk;
      } else {
        _Float16* outp = (z == 0) ? qh : kh;
        float scale = (z == 0) ? LOG2E : 1.0f;
#pragma unroll
        for (int r = 0; r < 4; ++r) {
          float x = acc[i][j][r];
          x = ((x > 0.f) ? (x + 1.f) : __expf(x)) * scale;
          outp[((size_t)(b * NH_ + h) * S_ + sl0 + r) * HD_ + d] = (_Float16)x;
        }
      }
    }
  }
}

// ---------------- Flash attention ------------------------------------------
// grid (S/128=16, B*NH=32) block 256 (4 waves, 32 q-rows each), BC=128.
// Swapped-operand scheme: QK computes S^T (mfma A=K,B=Q); P^T feeds PV
// directly from registers via 16x16x16 MFMA (no P LDS round-trip).
// T15 pipeline: PV runs ONE TILE BEHIND, interleaved in source with the
// softmax core (max/exp/sum) of the current tile -- these are independent
// (softmax-core never touches o), so the wave fills MFMA-pipe stall cycles
// with VALU. The alpha-rescale of o runs AFTER PV(t-1):
// o_new = alpha_t * (o + PV(t-1)) -- exact same math as the serial order.
// K double-buffered (ring-2); V ring-3 (PV(t-1) reads slot (t-1)%3 while
// the DMA for tile t+1 lands in slot (t+1)%3 -- disjoint). LDS = 80 KB.
__global__ __launch_bounds__(256, 2) void flash_attn(
    const _Float16* __restrict__ qh, const _Float16* __restrict__ kh,
    const _Float16* __restrict__ vt, const int* __restrict__ mask,
    _Float16* __restrict__ attn_out) {
  const int bh = blockIdx.y, b = bh >> 4, h = bh & 15;
  const int qbase = blockIdx.x * 128;
  const int tid = threadIdx.x, w = tid >> 6, lane = tid & 63;
  const int quad = lane >> 4, l16 = lane & 15;

  __shared__ _Float16 Kt[2][128 * 64];  // [key][d], slot = (d>>3)^(key&7)
  __shared__ _Float16 Vt[3][64 * 128];  // [d][key], slot = (key>>3)^(d&15)

  const _Float16* Q = qh + (size_t)bh * (S_ * HD_);
  const _Float16* K = kh + (size_t)bh * (S_ * HD_);
  const _Float16* Vg = vt + (size_t)bh * (HD_ * S_);
  const int* Mb = mask + b * S_;

  // Q B-fragments (2 row-groups of 16 q) in registers for the whole kernel
  half8 qf[2][2];
#pragma unroll
  for (int g = 0; g < 2; ++g) {
    int qr = qbase + w * 32 + g * 16 + l16;
    qf[g][0] = *(const half8*)&Q[qr * 64 + quad * 8];
    qf[g][1] = *(const half8*)&Q[qr * 64 + 32 + quad * 8];
  }

  floatx4 zero = {0.f, 0.f, 0.f, 0.f};
  floatx4 o[2][4];  // O^T[d = ct2*16 + quad*4 + r][q = l16 (group g)]
#pragma unroll
  for (int g = 0; g < 2; ++g)
#pragma unroll
    for (int i = 0; i < 4; ++i) o[g][i] = zero;
  float mi[2] = {-3e38f, -3e38f}, li[2] = {0.f, 0.f};

  // staging constants
  const int krow_off = lane >> 3;             // 0..7
  const int kslot = lane & 7;
  const int kchunk = kslot ^ (krow_off & 7);
  const int vrow_off = lane >> 4;             // 0..3
  const int vslot = lane & 15;

  // prologue: stage tile 0 into K-buf 0 / V-slot 0
  {
#pragma unroll
    for (int u = 0; u < 4; ++u) {
      int kl = w * 32 + u * 8;
      async_copy16(&Kt[0][kl * 64], K + (size_t)(kl + krow_off) * 64 + kchunk * 8);
    }
#pragma unroll
    for (int u = 0; u < 4; ++u) {
      int d0 = w * 16 + u * 4 + vrow_off;
      int c0 = vslot ^ (d0 & 15);
      async_copy16(&Vt[0][(w * 16 + u * 4) * 128], Vg + (size_t)d0 * S_ + c0 * 8);
    }
  }

  const int s0 = quad ^ (l16 & 7);
  const int s1 = (4 + quad) ^ (l16 & 7);

  half4_t pA[2][8], pB[2][8];  // P^T fragments, double-state (named; rule #20)

  // One pipelined tile step. pin = P of tile kt-1 (consumed by PV),
  // pout = P of tile kt (produced). vprev/vcur/vnext = V ring slots of
  // tiles kt-1 / kt / kt+1.
  auto TILE = [&](int kt, half4_t (&pin)[2][8], half4_t (&pout)[2][8],
                  int vprev, int vnext, bool dopv) {
    const int key0 = kt * 128;
    // barrier: compiler-inserted vmcnt(0) drains our DMA (issued a full
    // tile ago -> latency hidden); barrier makes all waves' DMA visible
    // and fences readers of the buffers we are about to overwrite.
    __syncthreads();
    if (kt < S_ / 128 - 1) {
      const int key1 = key0 + 128;
      _Float16* Kd = &Kt[(kt + 1) & 1][0];
      _Float16* Vd = &Vt[vnext][0];
#pragma unroll
      for (int u = 0; u < 4; ++u) {
        int kl = w * 32 + u * 8;
        async_copy16(Kd + kl * 64,
                     K + (size_t)(key1 + kl + krow_off) * 64 + kchunk * 8);
      }
#pragma unroll
      for (int u = 0; u < 4; ++u) {
        int d0 = w * 16 + u * 4 + vrow_off;
        int c0 = vslot ^ (d0 & 15);
        async_copy16(Vd + (w * 16 + u * 4) * 128,
                     Vg + (size_t)d0 * S_ + key1 + c0 * 8);
      }
    }
    int m0 = Mb[key0 + lane];
    int m1 = Mb[key0 + 64 + lane];

    const _Float16* Kb = &Kt[kt & 1][0];
    const _Float16* Vb = &Vt[vprev][0];

    // S^T tile: mfma(A=K-frag, B=Q-frag) -> S^T[key=ct*16+quad*4+r][q=l16]
    floatx4 sb[2][8];
#pragma unroll
    for (int g = 0; g < 2; ++g)
#pragma unroll
      for (int ct = 0; ct < 8; ++ct) sb[g][ct] = zero;
#pragma unroll
    for (int ct = 0; ct < 8; ++ct) {
      int key = ct * 16 + l16;
      half8 bf0 = *(half8*)&Kb[key * 64 + s0 * 8];
      half8 bf1 = *(half8*)&Kb[key * 64 + s1 * 8];
      sb[0][ct] = __builtin_amdgcn_mfma_f32_16x16x32_f16(bf0, qf[0][0], sb[0][ct], 0, 0, 0);
      sb[0][ct] = __builtin_amdgcn_mfma_f32_16x16x32_f16(bf1, qf[0][1], sb[0][ct], 0, 0, 0);
      sb[1][ct] = __builtin_amdgcn_mfma_f32_16x16x32_f16(bf0, qf[1][0], sb[1][ct], 0, 0, 0);
      sb[1][ct] = __builtin_amdgcn_mfma_f32_16x16x32_f16(bf1, qf[1][1], sb[1][ct], 0, 0, 0);
    }
    // masking (fast path: tile fully unmasked). key = ct*16 + quad*4 + r
    if (__any((m0 == 0) || (m1 == 0))) {
#pragma unroll
      for (int ct = 0; ct < 8; ++ct)
#pragma unroll
        for (int r = 0; r < 4; ++r)
          if (Mb[key0 + ct * 16 + quad * 4 + r] == 0) {
            sb[0][ct][r] = -1e30f;
            sb[1][ct][r] = -1e30f;
          }
    }

    // ---- interleave PV(t-1) with softmax-core(t) ----
    // PV: O^T += mfma(A=V^T-frag, B=P^T(t-1)-frag) over 8 key-chunks of 16.
#define PVC(ct)                                                              \
  if (dopv) {                                                                \
    int chunk = (2 * (ct) + (quad >> 1)) ^ l16;                              \
    int off = chunk * 8 + (quad & 1) * 4;                                    \
    _Pragma("unroll") for (int ct2 = 0; ct2 < 4; ++ct2) {                    \
      int d = ct2 * 16 + l16;                                                \
      half4_t vf = *(half4_t*)&Vb[d * 128 + off];                            \
      o[0][ct2] = __builtin_amdgcn_mfma_f32_16x16x16f16(vf, pin[0][ct],      \
                                                        o[0][ct2], 0, 0, 0); \
      o[1][ct2] = __builtin_amdgcn_mfma_f32_16x16x16f16(vf, pin[1][ct],      \
                                                        o[1][ct2], 0, 0, 0); \
    }                                                                        \
  }

    PVC(0); PVC(1);
    float tt[2][8];
#pragma unroll
    for (int g = 0; g < 2; ++g)
#pragma unroll
      for (int ct = 0; ct < 8; ++ct)
        tt[g][ct] = fmaxf(fmaxf(sb[g][ct][0], sb[g][ct][1]),
                          fmaxf(sb[g][ct][2], sb[g][ct][3]));
    PVC(2); PVC(3);
    float mx[2], mn[2], alpha[2];
#pragma unroll
    for (int g = 0; g < 2; ++g) {
      float m = fmaxf(fmaxf(fmaxf(tt[g][0], tt[g][1]), fmaxf(tt[g][2], tt[g][3])),
                      fmaxf(fmaxf(tt[g][4], tt[g][5]), fmaxf(tt[g][6], tt[g][7])));
      m = fmaxf(m, __shfl_xor(m, 16));
      mx[g] = fmaxf(m, __shfl_xor(m, 32));
    }
    PVC(4); PVC(5);
#pragma unroll
    for (int g = 0; g < 2; ++g) {
      mn[g] = fmaxf(mi[g], mx[g]);
      alpha[g] = __builtin_amdgcn_exp2f(mi[g] - mn[g]);
    }
    PVC(6); PVC(7);
    float rs[2];
#pragma unroll
    for (int g = 0; g < 2; ++g) {
      float r0 = 0.f, r1 = 0.f, r2 = 0.f, r3 = 0.f;
#pragma unroll
      for (int ct = 0; ct < 8; ++ct) {
        float p0 = __builtin_amdgcn_exp2f(sb[g][ct][0] - mn[g]);
        float p1 = __builtin_amdgcn_exp2f(sb[g][ct][1] - mn[g]);
        float p2 = __builtin_amdgcn_exp2f(sb[g][ct][2] - mn[g]);
        float p3 = __builtin_amdgcn_exp2f(sb[g][ct][3] - mn[g]);
        sb[g][ct][0] = p0; sb[g][ct][1] = p1;
        sb[g][ct][2] = p2; sb[g][ct][3] = p3;
        r0 += p0; r1 += p1; r2 += p2; r3 += p3;
      }
      float s = (r0 + r1) + (r2 + r3);
      s += __shfl_xor(s, 16);
      rs[g] = s + __shfl_xor(s, 32);
    }
#undef PVC
    // PV(t-1) fully accumulated; now bring o to scale m_t.
#pragma unroll
    for (int g = 0; g < 2; ++g) {
      mi[g] = mn[g];
      li[g] = li[g] * alpha[g] + rs[g];
#pragma unroll
      for (int ct2 = 0; ct2 < 4; ++ct2) {
        o[g][ct2][0] *= alpha[g]; o[g][ct2][1] *= alpha[g];
        o[g][ct2][2] *= alpha[g]; o[g][ct2][3] *= alpha[g];
      }
    }
    // cvt P(t) -> pout for next tile's PV
#pragma unroll
    for (int g = 0; g < 2; ++g)
#pragma unroll
      for (int ct = 0; ct < 8; ++ct) {
        half4_t pk;
#pragma unroll
        for (int r = 0; r < 4; ++r) pk[r] = (_Float16)sb[g][ct][r];
        pout[g][ct] = pk;
      }
  };

  // main loop, unrolled by 2 for static pA/pB alternation.
  // V ring slots: tile kt lives in slot kt%3.
  int vcur = 0;
  for (int k2 = 0; k2 < S_ / 128; k2 += 2) {
    int vnext = (vcur == 2) ? 0 : vcur + 1;
    int vprev = (vcur == 0) ? 2 : vcur - 1;
    TILE(k2, pB, pA, vprev, vnext, k2 > 0);
    int vcur1 = vnext;
    int vnext1 = (vcur1 == 2) ? 0 : vcur1 + 1;
    TILE(k2 + 1, pA, pB, vcur, vnext1, true);
    vcur = vnext1;
  }
  // drain: PV of the last tile (15). Slot 15%3 == 0; its data was staged at
  // iter 14 and synced at iter 15's barrier -- still intact (no DMA since).
  {
    const _Float16* Vb = &Vt[0][0];
#pragma unroll
    for (int ct = 0; ct < 8; ++ct) {
      int chunk = (2 * ct + (quad >> 1)) ^ l16;
      int off = chunk * 8 + (quad & 1) * 4;
#pragma unroll
      for (int ct2 = 0; ct2 < 4; ++ct2) {
        int d = ct2 * 16 + l16;
        half4_t vf = *(half4_t*)&Vb[d * 128 + off];
        o[0][ct2] = __builtin_amdgcn_mfma_f32_16x16x16f16(vf, pB[0][ct], o[0][ct2], 0, 0, 0);
        o[1][ct2] = __builtin_amdgcn_mfma_f32_16x16x16f16(vf, pB[1][ct], o[1][ct2], 0, 0, 0);
      }
    }
  }
  // epilogue: normalize, store (B, S, H) fp16 — half4 stores (d contiguous)
#pragma unroll
  for (int g = 0; g < 2; ++g) {
    float inv = 1.0f / li[g];
    int row = qbase + w * 32 + g * 16 + l16;
#pragma unroll
    for (int ct2 = 0; ct2 < 4; ++ct2) {
      half4_t pk;
#pragma unroll
      for (int r = 0; r < 4; ++r) pk[r] = (_Float16)(o[g][ct2][r] * inv);
      int d = ct2 * 16 + quad * 4;
      *(half4_t*)&attn_out[((size_t)(b * S_ + row)) * H_ + h * HD_ + d] = pk;
    }
  }
}

// ---------------- Output GEMM: out = AO @ Wo^T (fp32 out) ------------------
// grid (16, 32) block 256: 128x64 tiles -> 512 blocks (2/CU)
__global__ __launch_bounds__(256) void out_gemm(
    const _Float16* __restrict__ A, const _Float16* __restrict__ W,
    float* __restrict__ out) {
  const int rbase = blockIdx.y * 128;
  const int cbase = blockIdx.x * 64;
  __shared__ _Float16 As[128 * 32];
  __shared__ _Float16 Bs[64 * 32];
  const int tid = threadIdx.x, lane = tid & 63, w = tid >> 6;
  const int quad = lane >> 4, l16 = lane & 15;

  floatx4 zero = {0.f, 0.f, 0.f, 0.f};
  floatx4 acc[2][4];
#pragma unroll
  for (int i = 0; i < 2; ++i)
#pragma unroll
    for (int j = 0; j < 4; ++j) acc[i][j] = zero;

  const int srowA = w * 32 + (lane >> 2);
  const int srowB = w * 16 + (lane >> 2);
  const int sseg = (lane & 3) * 8;
  const _Float16* Ag = A + (size_t)(rbase + srowA) * H_ + sseg;
  const _Float16* Bg = W + (size_t)(cbase + srowB) * H_ + sseg;

  for (int k0 = 0; k0 < H_; k0 += 32) {
    async_copy16(&As[(w * 32) * 32], Ag + k0);
    async_copy16(&As[(w * 32 + 16) * 32], Ag + 16 * H_ + k0);
    async_copy16(&Bs[(w * 16) * 32], Bg + k0);
    __syncthreads();
    half8 af[2], bf[4];
#pragma unroll
    for (int t = 0; t < 2; ++t)
      af[t] = *(half8*)&As[(w * 32 + t * 16 + l16) * 32 + quad * 8];
#pragma unroll
    for (int t = 0; t < 4; ++t)
      bf[t] = *(half8*)&Bs[(t * 16 + l16) * 32 + quad * 8];
#pragma unroll
    for (int i = 0; i < 2; ++i)
#pragma unroll
      for (int j = 0; j < 4; ++j)
        acc[i][j] = __builtin_amdgcn_mfma_f32_16x16x32_f16(af[i], bf[j],
                                                           acc[i][j], 0, 0, 0);
    __syncthreads();
  }
#pragma unroll
  for (int i = 0; i < 2; ++i) {
    int r0 = rbase + w * 32 + i * 16 + quad * 4;
#pragma unroll
    for (int j = 0; j < 4; ++j) {
      int col = cbase + j * 16 + l16;
#pragma unroll
      for (int r = 0; r < 4; ++r)
        out[(size_t)(r0 + r) * H_ + col] = acc[i][j][r];
    }
  }
}

extern "C" void kernel_launch(void* const* d_in, const int* in_sizes, int n_in,
                              void* d_out, int out_size, void* d_ws,
                              size_t ws_size, hipStream_t stream) {
  const float* hs = (const float*)d_in[0];
  const int* mask = (const int*)d_in[1];
  const float* Wq = (const float*)d_in[2];
  const float* Wk = (const float*)d_in[3];
  const float* Wv = (const float*)d_in[4];
  const float* Wo = (const float*)d_in[5];
  float* out = (float*)d_out;

  _Float16* p = (_Float16*)d_ws;
  _Float16* hs_h = p; p += (size_t)BS_ * H_;
  _Float16* w_h = p;  p += (size_t)4 * H_ * H_;
  _Float16* q_h = p;  p += (size_t)BS_ * H_;
  _Float16* k_h = p;  p += (size_t)BS_ * H_;
  _Float16* v_t = p;  p += (size_t)BS_ * H_;
  _Float16* ao_h = p; p += (size_t)BS_ * H_;

  cvt_all<<<8192, 256, 0, stream>>>(hs, Wq, Wk, Wv, Wo, hs_h, w_h);
  qkv_gemm<<<dim3(8, 32, 3), 256, 0, stream>>>(hs_h, w_h, q_h, k_h, v_t);
  flash_attn<<<dim3(16, 32), 256, 0, stream>>>(q_h, k_h, v_t, mask, ao_h);
  out_gemm<<<dim3(16, 32), 256, 0, stream>>>(ao_h, w_h + (size_t)3 * H_ * H_, out);
}

// Round 6
// 192.562 us; speedup vs baseline: 1.0684x; 1.0304x over previous
//
#include <hip/hip_runtime.h>

#define H_ 1024
#define NH_ 16
#define HD_ 64
#define B_ 2
#define S_ 2048
#define BS_ 4096

typedef _Float16 half8 __attribute__((ext_vector_type(8)));
typedef _Float16 half4_t __attribute__((ext_vector_type(4)));
typedef float floatx4 __attribute__((ext_vector_type(4)));

#define LOG2E 1.44269504088896f

__device__ __forceinline__ void async_copy16(void* lds, const void* g) {
  __builtin_amdgcn_global_load_lds(
      (const __attribute__((address_space(1))) unsigned int*)g,
      (__attribute__((address_space(3))) unsigned int*)lds, 16, 0, 0);
}

// ---------------- fp32 -> fp16 conversion (hs + 4 weights) ----------------
__global__ __launch_bounds__(256) void cvt_all(
    const float* __restrict__ hs, const float* __restrict__ wq,
    const float* __restrict__ wk, const float* __restrict__ wv,
    const float* __restrict__ wo,
    _Float16* __restrict__ hs_h, _Float16* __restrict__ w_h) {
  int i = blockIdx.x * 256 + threadIdx.x;
  int idx = i * 4;
  const float* src; _Float16* dst; int off;
  if (idx < BS_ * H_) {
    src = hs; dst = hs_h; off = idx;
  } else {
    int j = idx - BS_ * H_;
    int w = j >> 20;
    off = j & ((1 << 20) - 1);
    src = (w == 0) ? wq : (w == 1) ? wk : (w == 2) ? wv : wo;
    dst = w_h + (size_t)w * (H_ * H_);
  }
  float4 f = *(const float4*)(src + off);
  half4_t o;
  o.x = (_Float16)f.x; o.y = (_Float16)f.y;
  o.z = (_Float16)f.z; o.w = (_Float16)f.w;
  *(half4_t*)(dst + off) = o;
}

// ---------------- QKV GEMM: C = A @ W^T ------------------------------------
// grid (8, 32, 3) block 256 (4 waves), 128x128 tile, BK=32, 32 K-iters.
// Ring-3 K-tile LDS (48 KB -> 3 blocks/CU), stage-ahead-2, counted
// s_waitcnt vmcnt(4) (never 0 in main loop) + raw s_barrier: 8 loads stay
// in flight across barriers (T4). LDS reads XOR-swizzled via pre-swizzled
// global source (T2): read slot = quad ^ ((row>>1)&3) -> 2-way max (free).
// Barrier-before-STAGE fences readers of the slot being overwritten
// ((t+2)%3 == (t-1)%3, whose readers ran before this barrier).
__global__ __launch_bounds__(256, 3) void qkv_gemm(
    const _Float16* __restrict__ A, const _Float16* __restrict__ Wall,
    _Float16* __restrict__ qh, _Float16* __restrict__ kh,
    _Float16* __restrict__ vt) {
  const int z = blockIdx.z;
  const _Float16* W = Wall + (size_t)z * (H_ * H_);
  const int rbase = blockIdx.y * 128;
  const int cbase = blockIdx.x * 128;
  __shared__ _Float16 Ab[3][128 * 32];
  __shared__ _Float16 Bb[3][128 * 32];
  const int tid = threadIdx.x, lane = tid & 63, w = tid >> 6;
  const int quad = lane >> 4, l16 = lane & 15;
  const int wr = (w >> 1) * 64, wc = (w & 1) * 64;

  floatx4 zero = {0.f, 0.f, 0.f, 0.f};
  floatx4 acc[4][4];
#pragma unroll
  for (int i = 0; i < 4; ++i)
#pragma unroll
    for (int j = 0; j < 4; ++j) acc[i][j] = zero;

  // staging: chunk c = tid + u*256 -> LDS row c>>2, slot c&3. Dest byte
  // offset = c*16 (linear in tid, as global_load_lds requires). Source
  // col-slot pre-swizzled: sslot = pslot ^ ((row>>1)&3); row = srow + u*64
  // keeps the same sslot for both u (64/2 = 32 == 0 mod 4).
  const int srow = tid >> 2;   // 0..63 (+u*64)
  const int pslot = tid & 3;
  const int sslot = pslot ^ ((srow >> 1) & 3);
  const _Float16* Ag = A + (size_t)(rbase + srow) * H_ + sslot * 8;
  const _Float16* Bg = W + (size_t)(cbase + srow) * H_ + sslot * 8;

  auto STAGE = [&](int s, int t) {
    const int k0 = t * 32;
    _Float16* ab = &Ab[s][tid * 8];
    _Float16* bb = &Bb[s][tid * 8];
    async_copy16(ab, Ag + k0);
    async_copy16(ab + 2048, Ag + (size_t)64 * H_ + k0);
    async_copy16(bb, Bg + k0);
    async_copy16(bb + 2048, Bg + (size_t)64 * H_ + k0);
  };

  const int rsw = (l16 >> 1) & 3;  // (row>>1)&3 of fragment rows
  auto COMPUTE = [&](int s) {
    const _Float16* Ap = &Ab[s][0];
    const _Float16* Bp = &Bb[s][0];
    half8 af[4], bf[4];
#pragma unroll
    for (int t = 0; t < 4; ++t)
      af[t] = *(const half8*)&Ap[(wr + t * 16 + l16) * 32 + (quad ^ rsw) * 8];
#pragma unroll
    for (int t = 0; t < 4; ++t)
      bf[t] = *(const half8*)&Bp[(wc + t * 16 + l16) * 32 + (quad ^ rsw) * 8];
    __builtin_amdgcn_s_setprio(1);
#pragma unroll
    for (int i = 0; i < 4; ++i)
#pragma unroll
      for (int j = 0; j < 4; ++j)
        acc[i][j] = __builtin_amdgcn_mfma_f32_16x16x32_f16(af[i], bf[j],
                                                           acc[i][j], 0, 0, 0);
    __builtin_amdgcn_s_setprio(0);
  };

  STAGE(0, 0);
  STAGE(1, 1);
  int sc = 0;
  for (int t = 0; t < 30; ++t) {
    asm volatile("s_waitcnt vmcnt(4)" ::: "memory");
    __builtin_amdgcn_sched_barrier(0);
    __builtin_amdgcn_s_barrier();
    __builtin_amdgcn_sched_barrier(0);
    int ss = sc + 2; if (ss >= 3) ss -= 3;
    STAGE(ss, t + 2);
    COMPUTE(sc);
    sc = (sc == 2) ? 0 : sc + 1;
  }
  asm volatile("s_waitcnt vmcnt(4)" ::: "memory");
  __builtin_amdgcn_sched_barrier(0);
  __builtin_amdgcn_s_barrier();
  __builtin_amdgcn_sched_barrier(0);
  COMPUTE(sc);  // tile 30
  sc = (sc == 2) ? 0 : sc + 1;
  asm volatile("s_waitcnt vmcnt(0)" ::: "memory");
  __builtin_amdgcn_sched_barrier(0);
  __builtin_amdgcn_s_barrier();
  __builtin_amdgcn_sched_barrier(0);
  COMPUTE(sc);  // tile 31

  // epilogue
#pragma unroll
  for (int i = 0; i < 4; ++i) {
    int r0 = rbase + wr + i * 16 + quad * 4;
    int b = r0 >> 11, sl0 = r0 & (S_ - 1);
#pragma unroll
    for (int j = 0; j < 4; ++j) {
      int col = cbase + wc + j * 16 + l16;
      int h = col >> 6, d = col & 63;
      if (z == 2) {
        half4_t pk;
#pragma unroll
        for (int r = 0; r < 4; ++r) pk[r] = (_Float16)acc[i][j][r];
        *(half4_t*)&vt[((size_t)(b * NH_ + h) * HD_ + d) * S_ + sl0] = pk;
      } else {
        _Float16* outp = (z == 0) ? qh : kh;
        float scale = (z == 0) ? LOG2E : 1.0f;
#pragma unroll
        for (int r = 0; r < 4; ++r) {
          float x = acc[i][j][r];
          x = ((x > 0.f) ? (x + 1.f) : __expf(x)) * scale;
          outp[((size_t)(b * NH_ + h) * S_ + sl0 + r) * HD_ + d] = (_Float16)x;
        }
      }
    }
  }
}

// ---------------- Flash attention ------------------------------------------
// grid (S/128=16, B*NH=32) block 256 (4 waves, 32 q-rows each), BC=128.
// Swapped-operand scheme: QK computes S^T (mfma A=K,B=Q); P^T feeds PV
// directly from registers via 16x16x16 MFMA (no P LDS round-trip).
// K/V double-buffered via global_load_lds; ONE barrier per tile.
__global__ __launch_bounds__(256, 2) void flash_attn(
    const _Float16* __restrict__ qh, const _Float16* __restrict__ kh,
    const _Float16* __restrict__ vt, const int* __restrict__ mask,
    _Float16* __restrict__ attn_out) {
  const int bh = blockIdx.y, b = bh >> 4, h = bh & 15;
  const int qbase = blockIdx.x * 128;
  const int tid = threadIdx.x, w = tid >> 6, lane = tid & 63;
  const int quad = lane >> 4, l16 = lane & 15;

  __shared__ _Float16 Kt[2][128 * 64];  // [key][d], slot = (d>>3)^(key&7)
  __shared__ _Float16 Vt[2][64 * 128];  // [d][key], slot = (key>>3)^(d&15)

  const _Float16* Q = qh + (size_t)bh * (S_ * HD_);
  const _Float16* K = kh + (size_t)bh * (S_ * HD_);
  const _Float16* Vg = vt + (size_t)bh * (HD_ * S_);
  const int* Mb = mask + b * S_;

  // Q B-fragments (2 row-groups of 16 q) in registers for the whole kernel
  half8 qf[2][2];
#pragma unroll
  for (int g = 0; g < 2; ++g) {
    int qr = qbase + w * 32 + g * 16 + l16;
    qf[g][0] = *(const half8*)&Q[qr * 64 + quad * 8];
    qf[g][1] = *(const half8*)&Q[qr * 64 + 32 + quad * 8];
  }

  floatx4 zero = {0.f, 0.f, 0.f, 0.f};
  floatx4 o[2][4];  // O^T[d = ct2*16 + quad*4 + r][q = l16 (group g)]
#pragma unroll
  for (int g = 0; g < 2; ++g)
#pragma unroll
    for (int i = 0; i < 4; ++i) o[g][i] = zero;
  float mi[2] = {-3e38f, -3e38f}, li[2] = {0.f, 0.f};

  // staging constants
  const int krow_off = lane >> 3;             // 0..7
  const int kslot = lane & 7;
  const int kchunk = kslot ^ (krow_off & 7);
  const int vrow_off = lane >> 4;             // 0..3
  const int vslot = lane & 15;

  // prologue: stage tile 0 into buffer 0
  {
#pragma unroll
    for (int u = 0; u < 4; ++u) {
      int kl = w * 32 + u * 8;
      async_copy16(&Kt[0][kl * 64], K + (size_t)(kl + krow_off) * 64 + kchunk * 8);
    }
#pragma unroll
    for (int u = 0; u < 4; ++u) {
      int d0 = w * 16 + u * 4 + vrow_off;
      int c0 = vslot ^ (d0 & 15);
      async_copy16(&Vt[0][(w * 16 + u * 4) * 128], Vg + (size_t)d0 * S_ + c0 * 8);
    }
  }

  for (int kt = 0; kt < S_ / 128; ++kt) {
    const int key0 = kt * 128;
    const int buf = kt & 1;
    // barrier: compiler-inserted vmcnt(0) drains our DMA (issued a full tile
    // ago -> latency hidden); barrier makes all waves' DMA visible.
    __syncthreads();
    // prefetch next tile into the other buffer
    if (kt < S_ / 128 - 1) {
      const int key1 = key0 + 128;
#pragma unroll
      for (int u = 0; u < 4; ++u) {
        int kl = w * 32 + u * 8;
        async_copy16(&Kt[buf ^ 1][kl * 64],
                     K + (size_t)(key1 + kl + krow_off) * 64 + kchunk * 8);
      }
#pragma unroll
      for (int u = 0; u < 4; ++u) {
        int d0 = w * 16 + u * 4 + vrow_off;
        int c0 = vslot ^ (d0 & 15);
        async_copy16(&Vt[buf ^ 1][(w * 16 + u * 4) * 128],
                     Vg + (size_t)d0 * S_ + key1 + c0 * 8);
      }
    }
    int m0 = Mb[key0 + lane];
    int m1 = Mb[key0 + 64 + lane];

    const _Float16* Kb = &Kt[buf][0];
    const _Float16* Vb = &Vt[buf][0];

    // S^T tile: mfma(A=K-frag, B=Q-frag) -> S^T[key=ct*16+quad*4+r][q=l16]
    floatx4 sa[2][8];
#pragma unroll
    for (int g = 0; g < 2; ++g)
#pragma unroll
      for (int ct = 0; ct < 8; ++ct) sa[g][ct] = zero;
    {
      int s0 = quad ^ (l16 & 7);
      int s1 = (4 + quad) ^ (l16 & 7);
#pragma unroll
      for (int ct = 0; ct < 8; ++ct) {
        int key = ct * 16 + l16;
        half8 bf0 = *(half8*)&Kb[key * 64 + s0 * 8];
        half8 bf1 = *(half8*)&Kb[key * 64 + s1 * 8];
        sa[0][ct] = __builtin_amdgcn_mfma_f32_16x16x32_f16(bf0, qf[0][0], sa[0][ct], 0, 0, 0);
        sa[0][ct] = __builtin_amdgcn_mfma_f32_16x16x32_f16(bf1, qf[0][1], sa[0][ct], 0, 0, 0);
        sa[1][ct] = __builtin_amdgcn_mfma_f32_16x16x32_f16(bf0, qf[1][0], sa[1][ct], 0, 0, 0);
        sa[1][ct] = __builtin_amdgcn_mfma_f32_16x16x32_f16(bf1, qf[1][1], sa[1][ct], 0, 0, 0);
      }
    }
    // masking (fast path: tile fully unmasked). key = ct*16 + quad*4 + r
    if (__any((m0 == 0) || (m1 == 0))) {
#pragma unroll
      for (int ct = 0; ct < 8; ++ct)
#pragma unroll
        for (int r = 0; r < 4; ++r)
          if (Mb[key0 + ct * 16 + quad * 4 + r] == 0) {
            sa[0][ct][r] = -1e30f;
            sa[1][ct][r] = -1e30f;
          }
    }
    // online softmax per q-column (in-lane over 32 logits + 2 shuffles)
#pragma unroll
    for (int g = 0; g < 2; ++g) {
      float mx = sa[g][0][0];
#pragma unroll
      for (int ct = 0; ct < 8; ++ct)
#pragma unroll
        for (int r = 0; r < 4; ++r) mx = fmaxf(mx, sa[g][ct][r]);
      mx = fmaxf(mx, __shfl_xor(mx, 16));
      mx = fmaxf(mx, __shfl_xor(mx, 32));
      float mn = fmaxf(mi[g], mx);
      float alpha = __builtin_amdgcn_exp2f(mi[g] - mn);
      mi[g] = mn;
      float rs = 0.f;
#pragma unroll
      for (int ct = 0; ct < 8; ++ct)
#pragma unroll
        for (int r = 0; r < 4; ++r) {
          float p = __builtin_amdgcn_exp2f(sa[g][ct][r] - mn);
          sa[g][ct][r] = p;
          rs += p;
        }
      rs += __shfl_xor(rs, 16);
      rs += __shfl_xor(rs, 32);
      li[g] = li[g] * alpha + rs;
#pragma unroll
      for (int ct2 = 0; ct2 < 4; ++ct2) {
        o[g][ct2][0] *= alpha; o[g][ct2][1] *= alpha;
        o[g][ct2][2] *= alpha; o[g][ct2][3] *= alpha;
      }
    }
    // PV: O^T += mfma(A=V^T-frag, B=P^T-frag) over 8 key-chunks of 16.
    // P^T C-layout (key=quad*4+r) IS the 16x16x16 B-operand layout.
#pragma unroll
    for (int ct = 0; ct < 8; ++ct) {
      half4_t p0, p1;
#pragma unroll
      for (int r = 0; r < 4; ++r) {
        p0[r] = (_Float16)sa[0][ct][r];
        p1[r] = (_Float16)sa[1][ct][r];
      }
      int chunk = (2 * ct + (quad >> 1)) ^ l16;  // key-chunk swizzled by d&15
      int off = chunk * 8 + (quad & 1) * 4;
#pragma unroll
      for (int ct2 = 0; ct2 < 4; ++ct2) {
        int d = ct2 * 16 + l16;
        half4_t vf = *(half4_t*)&Vb[d * 128 + off];
        o[0][ct2] = __builtin_amdgcn_mfma_f32_16x16x16f16(vf, p0, o[0][ct2], 0, 0, 0);
        o[1][ct2] = __builtin_amdgcn_mfma_f32_16x16x16f16(vf, p1, o[1][ct2], 0, 0, 0);
      }
    }
  }
  // epilogue: normalize, store (B, S, H) fp16 — half4 stores (d contiguous)
#pragma unroll
  for (int g = 0; g < 2; ++g) {
    float inv = 1.0f / li[g];
    int row = qbase + w * 32 + g * 16 + l16;
#pragma unroll
    for (int ct2 = 0; ct2 < 4; ++ct2) {
      half4_t pk;
#pragma unroll
      for (int r = 0; r < 4; ++r) pk[r] = (_Float16)(o[g][ct2][r] * inv);
      int d = ct2 * 16 + quad * 4;
      *(half4_t*)&attn_out[((size_t)(b * S_ + row)) * H_ + h * HD_ + d] = pk;
    }
  }
}

// ---------------- Output GEMM: out = AO @ Wo^T (fp32 out) ------------------
// grid (16, 32) block 256: 128x64 tiles. Ring-3 counted-vmcnt pipeline
// (36 KB LDS -> 4 blocks/CU), same schedule as qkv_gemm; STAGE = 3 loads
// (2 A + 1 B) -> wait vmcnt(3) in main loop.
__global__ __launch_bounds__(256, 2) void out_gemm(
    const _Float16* __restrict__ A, const _Float16* __restrict__ W,
    float* __restrict__ out) {
  const int rbase = blockIdx.y * 128;
  const int cbase = blockIdx.x * 64;
  __shared__ _Float16 Ab[3][128 * 32];
  __shared__ _Float16 Bb[3][64 * 32];
  const int tid = threadIdx.x, lane = tid & 63, w = tid >> 6;
  const int quad = lane >> 4, l16 = lane & 15;

  floatx4 zero = {0.f, 0.f, 0.f, 0.f};
  floatx4 acc[2][4];
#pragma unroll
  for (int i = 0; i < 2; ++i)
#pragma unroll
    for (int j = 0; j < 4; ++j) acc[i][j] = zero;

  const int srow = tid >> 2;   // 0..63 (+u*64 for A)
  const int pslot = tid & 3;
  const int sslot = pslot ^ ((srow >> 1) & 3);
  const _Float16* Ag = A + (size_t)(rbase + srow) * H_ + sslot * 8;
  const _Float16* Bg = W + (size_t)(cbase + srow) * H_ + sslot * 8;

  auto STAGE = [&](int s, int t) {
    const int k0 = t * 32;
    _Float16* ab = &Ab[s][tid * 8];
    async_copy16(ab, Ag + k0);
    async_copy16(ab + 2048, Ag + (size_t)64 * H_ + k0);
    async_copy16(&Bb[s][tid * 8], Bg + k0);
  };

  const int rsw = (l16 >> 1) & 3;
  auto COMPUTE = [&](int s) {
    const _Float16* Ap = &Ab[s][0];
    const _Float16* Bp = &Bb[s][0];
    half8 af[2], bf[4];
#pragma unroll
    for (int t = 0; t < 2; ++t)
      af[t] = *(const half8*)&Ap[(w * 32 + t * 16 + l16) * 32 + (quad ^ rsw) * 8];
#pragma unroll
    for (int t = 0; t < 4; ++t)
      bf[t] = *(const half8*)&Bp[(t * 16 + l16) * 32 + (quad ^ rsw) * 8];
    __builtin_amdgcn_s_setprio(1);
#pragma unroll
    for (int i = 0; i < 2; ++i)
#pragma unroll
      for (int j = 0; j < 4; ++j)
        acc[i][j] = __builtin_amdgcn_mfma_f32_16x16x32_f16(af[i], bf[j],
                                                           acc[i][j], 0, 0, 0);
    __builtin_amdgcn_s_setprio(0);
  };

  STAGE(0, 0);
  STAGE(1, 1);
  int sc = 0;
  for (int t = 0; t < 30; ++t) {
    asm volatile("s_waitcnt vmcnt(3)" ::: "memory");
    __builtin_amdgcn_sched_barrier(0);
    __builtin_amdgcn_s_barrier();
    __builtin_amdgcn_sched_barrier(0);
    int ss = sc + 2; if (ss >= 3) ss -= 3;
    STAGE(ss, t + 2);
    COMPUTE(sc);
    sc = (sc == 2) ? 0 : sc + 1;
  }
  asm volatile("s_waitcnt vmcnt(3)" ::: "memory");
  __builtin_amdgcn_sched_barrier(0);
  __builtin_amdgcn_s_barrier();
  __builtin_amdgcn_sched_barrier(0);
  COMPUTE(sc);  // tile 30
  sc = (sc == 2) ? 0 : sc + 1;
  asm volatile("s_waitcnt vmcnt(0)" ::: "memory");
  __builtin_amdgcn_sched_barrier(0);
  __builtin_amdgcn_s_barrier();
  __builtin_amdgcn_sched_barrier(0);
  COMPUTE(sc);  // tile 31

#pragma unroll
  for (int i = 0; i < 2; ++i) {
    int r0 = rbase + w * 32 + i * 16 + quad * 4;
#pragma unroll
    for (int j = 0; j < 4; ++j) {
      int col = cbase + j * 16 + l16;
#pragma unroll
      for (int r = 0; r < 4; ++r)
        out[(size_t)(r0 + r) * H_ + col] = acc[i][j][r];
    }
  }
}

extern "C" void kernel_launch(void* const* d_in, const int* in_sizes, int n_in,
                              void* d_out, int out_size, void* d_ws,
                              size_t ws_size, hipStream_t stream) {
  const float* hs = (const float*)d_in[0];
  const int* mask = (const int*)d_in[1];
  const float* Wq = (const float*)d_in[2];
  const float* Wk = (const float*)d_in[3];
  const float* Wv = (const float*)d_in[4];
  const float* Wo = (const float*)d_in[5];
  float* out = (float*)d_out;

  _Float16* p = (_Float16*)d_ws;
  _Float16* hs_h = p; p += (size_t)BS_ * H_;
  _Float16* w_h = p;  p += (size_t)4 * H_ * H_;
  _Float16* q_h = p;  p += (size_t)BS_ * H_;
  _Float16* k_h = p;  p += (size_t)BS_ * H_;
  _Float16* v_t = p;  p += (size_t)BS_ * H_;
  _Float16* ao_h = p; p += (size_t)BS_ * H_;

  cvt_all<<<8192, 256, 0, stream>>>(hs, Wq, Wk, Wv, Wo, hs_h, w_h);
  qkv_gemm<<<dim3(8, 32, 3), 256, 0, stream>>>(hs_h, w_h, q_h, k_h, v_t);
  flash_attn<<<dim3(16, 32), 256, 0, stream>>>(q_h, k_h, v_t, mask, ao_h);
  out_gemm<<<dim3(16, 32), 256, 0, stream>>>(ao_h, w_h + (size_t)3 * H_ * H_, out);
}

// Round 7
// 186.115 us; speedup vs baseline: 1.1055x; 1.0346x over previous
//
#include <hip/hip_runtime.h>

#define H_ 1024
#define NH_ 16
#define HD_ 64
#define B_ 2
#define S_ 2048
#define BS_ 4096

typedef _Float16 half8 __attribute__((ext_vector_type(8)));
typedef _Float16 half4_t __attribute__((ext_vector_type(4)));
typedef float floatx4 __attribute__((ext_vector_type(4)));

#define LOG2E 1.44269504088896f

__device__ __forceinline__ void async_copy16(void* lds, const void* g) {
  __builtin_amdgcn_global_load_lds(
      (const __attribute__((address_space(1))) unsigned int*)g,
      (__attribute__((address_space(3))) unsigned int*)lds, 16, 0, 0);
}

// ---------------- fp32 -> fp16 conversion (hs + 4 weights) ----------------
__global__ __launch_bounds__(256) void cvt_all(
    const float* __restrict__ hs, const float* __restrict__ wq,
    const float* __restrict__ wk, const float* __restrict__ wv,
    const float* __restrict__ wo,
    _Float16* __restrict__ hs_h, _Float16* __restrict__ w_h) {
  int i = blockIdx.x * 256 + threadIdx.x;
  int idx = i * 4;
  const float* src; _Float16* dst; int off;
  if (idx < BS_ * H_) {
    src = hs; dst = hs_h; off = idx;
  } else {
    int j = idx - BS_ * H_;
    int w = j >> 20;
    off = j & ((1 << 20) - 1);
    src = (w == 0) ? wq : (w == 1) ? wk : (w == 2) ? wv : wo;
    dst = w_h + (size_t)w * (H_ * H_);
  }
  float4 f = *(const float4*)(src + off);
  half4_t o;
  o.x = (_Float16)f.x; o.y = (_Float16)f.y;
  o.z = (_Float16)f.z; o.w = (_Float16)f.w;
  *(half4_t*)(dst + off) = o;
}

// ---------------- QKV GEMM: C = A @ W^T ------------------------------------
// grid (8, 32, 3) block 256 (4 waves), 128x128 tile, BK=32, 32 K-iters.
// Ring-3 K-tile LDS (48 KB -> 3 blocks/CU), stage-ahead-2, counted
// s_waitcnt vmcnt(4) (never 0 in main loop) + raw s_barrier (T4).
// LDS reads XOR-swizzled via pre-swizzled global source (T2).
__global__ __launch_bounds__(256, 3) void qkv_gemm(
    const _Float16* __restrict__ A, const _Float16* __restrict__ Wall,
    _Float16* __restrict__ qh, _Float16* __restrict__ kh,
    _Float16* __restrict__ vt) {
  const int z = blockIdx.z;
  const _Float16* W = Wall + (size_t)z * (H_ * H_);
  const int rbase = blockIdx.y * 128;
  const int cbase = blockIdx.x * 128;
  __shared__ _Float16 Ab[3][128 * 32];
  __shared__ _Float16 Bb[3][128 * 32];
  const int tid = threadIdx.x, lane = tid & 63, w = tid >> 6;
  const int quad = lane >> 4, l16 = lane & 15;
  const int wr = (w >> 1) * 64, wc = (w & 1) * 64;

  floatx4 zero = {0.f, 0.f, 0.f, 0.f};
  floatx4 acc[4][4];
#pragma unroll
  for (int i = 0; i < 4; ++i)
#pragma unroll
    for (int j = 0; j < 4; ++j) acc[i][j] = zero;

  const int srow = tid >> 2;   // 0..63 (+u*64)
  const int pslot = tid & 3;
  const int sslot = pslot ^ ((srow >> 1) & 3);
  const _Float16* Ag = A + (size_t)(rbase + srow) * H_ + sslot * 8;
  const _Float16* Bg = W + (size_t)(cbase + srow) * H_ + sslot * 8;

  auto STAGE = [&](int s, int t) {
    const int k0 = t * 32;
    _Float16* ab = &Ab[s][tid * 8];
    _Float16* bb = &Bb[s][tid * 8];
    async_copy16(ab, Ag + k0);
    async_copy16(ab + 2048, Ag + (size_t)64 * H_ + k0);
    async_copy16(bb, Bg + k0);
    async_copy16(bb + 2048, Bg + (size_t)64 * H_ + k0);
  };

  const int rsw = (l16 >> 1) & 3;  // (row>>1)&3 of fragment rows
  auto COMPUTE = [&](int s) {
    const _Float16* Ap = &Ab[s][0];
    const _Float16* Bp = &Bb[s][0];
    half8 af[4], bf[4];
#pragma unroll
    for (int t = 0; t < 4; ++t)
      af[t] = *(const half8*)&Ap[(wr + t * 16 + l16) * 32 + (quad ^ rsw) * 8];
#pragma unroll
    for (int t = 0; t < 4; ++t)
      bf[t] = *(const half8*)&Bp[(wc + t * 16 + l16) * 32 + (quad ^ rsw) * 8];
    __builtin_amdgcn_s_setprio(1);
#pragma unroll
    for (int i = 0; i < 4; ++i)
#pragma unroll
      for (int j = 0; j < 4; ++j)
        acc[i][j] = __builtin_amdgcn_mfma_f32_16x16x32_f16(af[i], bf[j],
                                                           acc[i][j], 0, 0, 0);
    __builtin_amdgcn_s_setprio(0);
  };

  STAGE(0, 0);
  STAGE(1, 1);
  int sc = 0;
  for (int t = 0; t < 30; ++t) {
    asm volatile("s_waitcnt vmcnt(4)" ::: "memory");
    __builtin_amdgcn_sched_barrier(0);
    __builtin_amdgcn_s_barrier();
    __builtin_amdgcn_sched_barrier(0);
    int ss = sc + 2; if (ss >= 3) ss -= 3;
    STAGE(ss, t + 2);
    COMPUTE(sc);
    sc = (sc == 2) ? 0 : sc + 1;
  }
  asm volatile("s_waitcnt vmcnt(4)" ::: "memory");
  __builtin_amdgcn_sched_barrier(0);
  __builtin_amdgcn_s_barrier();
  __builtin_amdgcn_sched_barrier(0);
  COMPUTE(sc);  // tile 30
  sc = (sc == 2) ? 0 : sc + 1;
  asm volatile("s_waitcnt vmcnt(0)" ::: "memory");
  __builtin_amdgcn_sched_barrier(0);
  __builtin_amdgcn_s_barrier();
  __builtin_amdgcn_sched_barrier(0);
  COMPUTE(sc);  // tile 31

  // epilogue
#pragma unroll
  for (int i = 0; i < 4; ++i) {
    int r0 = rbase + wr + i * 16 + quad * 4;
    int b = r0 >> 11, sl0 = r0 & (S_ - 1);
#pragma unroll
    for (int j = 0; j < 4; ++j) {
      int col = cbase + wc + j * 16 + l16;
      int h = col >> 6, d = col & 63;
      if (z == 2) {
        half4_t pk;
#pragma unroll
        for (int r = 0; r < 4; ++r) pk[r] = (_Float16)acc[i][j][r];
        *(half4_t*)&vt[((size_t)(b * NH_ + h) * HD_ + d) * S_ + sl0] = pk;
      } else {
        _Float16* outp = (z == 0) ? qh : kh;
        float scale = (z == 0) ? LOG2E : 1.0f;
#pragma unroll
        for (int r = 0; r < 4; ++r) {
          float x = acc[i][j][r];
          x = ((x > 0.f) ? (x + 1.f) : __expf(x)) * scale;
          outp[((size_t)(b * NH_ + h) * S_ + sl0 + r) * HD_ + d] = (_Float16)x;
        }
      }
    }
  }
}

// ---------------- Flash attention ------------------------------------------
// grid (S/128=16, B*NH=32) block 256 (4 waves, 32 q-rows each), BC=128.
// Swapped-operand scheme: QK computes S^T (mfma A=K,B=Q); P^T feeds PV
// directly from registers via 16x16x16 MFMA (no P LDS round-trip).
// K/V double-buffered via global_load_lds; ONE barrier per tile.
__global__ __launch_bounds__(256, 2) void flash_attn(
    const _Float16* __restrict__ qh, const _Float16* __restrict__ kh,
    const _Float16* __restrict__ vt, const int* __restrict__ mask,
    _Float16* __restrict__ attn_out) {
  const int bh = blockIdx.y, b = bh >> 4, h = bh & 15;
  const int qbase = blockIdx.x * 128;
  const int tid = threadIdx.x, w = tid >> 6, lane = tid & 63;
  const int quad = lane >> 4, l16 = lane & 15;

  __shared__ _Float16 Kt[2][128 * 64];  // [key][d], slot = (d>>3)^(key&7)
  __shared__ _Float16 Vt[2][64 * 128];  // [d][key], slot = (key>>3)^(d&15)

  const _Float16* Q = qh + (size_t)bh * (S_ * HD_);
  const _Float16* K = kh + (size_t)bh * (S_ * HD_);
  const _Float16* Vg = vt + (size_t)bh * (HD_ * S_);
  const int* Mb = mask + b * S_;

  // Q B-fragments (2 row-groups of 16 q) in registers for the whole kernel
  half8 qf[2][2];
#pragma unroll
  for (int g = 0; g < 2; ++g) {
    int qr = qbase + w * 32 + g * 16 + l16;
    qf[g][0] = *(const half8*)&Q[qr * 64 + quad * 8];
    qf[g][1] = *(const half8*)&Q[qr * 64 + 32 + quad * 8];
  }

  floatx4 zero = {0.f, 0.f, 0.f, 0.f};
  floatx4 o[2][4];  // O^T[d = ct2*16 + quad*4 + r][q = l16 (group g)]
#pragma unroll
  for (int g = 0; g < 2; ++g)
#pragma unroll
    for (int i = 0; i < 4; ++i) o[g][i] = zero;
  float mi[2] = {-3e38f, -3e38f}, li[2] = {0.f, 0.f};

  // staging constants
  const int krow_off = lane >> 3;             // 0..7
  const int kslot = lane & 7;
  const int kchunk = kslot ^ (krow_off & 7);
  const int vrow_off = lane >> 4;             // 0..3
  const int vslot = lane & 15;

  // prologue: stage tile 0 into buffer 0
  {
#pragma unroll
    for (int u = 0; u < 4; ++u) {
      int kl = w * 32 + u * 8;
      async_copy16(&Kt[0][kl * 64], K + (size_t)(kl + krow_off) * 64 + kchunk * 8);
    }
#pragma unroll
    for (int u = 0; u < 4; ++u) {
      int d0 = w * 16 + u * 4 + vrow_off;
      int c0 = vslot ^ (d0 & 15);
      async_copy16(&Vt[0][(w * 16 + u * 4) * 128], Vg + (size_t)d0 * S_ + c0 * 8);
    }
  }

  for (int kt = 0; kt < S_ / 128; ++kt) {
    const int key0 = kt * 128;
    const int buf = kt & 1;
    // barrier: compiler-inserted vmcnt(0) drains our DMA (issued a full tile
    // ago -> latency hidden); barrier makes all waves' DMA visible.
    __syncthreads();
    // prefetch next tile into the other buffer
    if (kt < S_ / 128 - 1) {
      const int key1 = key0 + 128;
#pragma unroll
      for (int u = 0; u < 4; ++u) {
        int kl = w * 32 + u * 8;
        async_copy16(&Kt[buf ^ 1][kl * 64],
                     K + (size_t)(key1 + kl + krow_off) * 64 + kchunk * 8);
      }
#pragma unroll
      for (int u = 0; u < 4; ++u) {
        int d0 = w * 16 + u * 4 + vrow_off;
        int c0 = vslot ^ (d0 & 15);
        async_copy16(&Vt[buf ^ 1][(w * 16 + u * 4) * 128],
                     Vg + (size_t)d0 * S_ + key1 + c0 * 8);
      }
    }
    int m0 = Mb[key0 + lane];
    int m1 = Mb[key0 + 64 + lane];

    const _Float16* Kb = &Kt[buf][0];
    const _Float16* Vb = &Vt[buf][0];

    // S^T tile: mfma(A=K-frag, B=Q-frag) -> S^T[key=ct*16+quad*4+r][q=l16]
    floatx4 sa[2][8];
#pragma unroll
    for (int g = 0; g < 2; ++g)
#pragma unroll
      for (int ct = 0; ct < 8; ++ct) sa[g][ct] = zero;
    {
      int s0 = quad ^ (l16 & 7);
      int s1 = (4 + quad) ^ (l16 & 7);
#pragma unroll
      for (int ct = 0; ct < 8; ++ct) {
        int key = ct * 16 + l16;
        half8 bf0 = *(half8*)&Kb[key * 64 + s0 * 8];
        half8 bf1 = *(half8*)&Kb[key * 64 + s1 * 8];
        sa[0][ct] = __builtin_amdgcn_mfma_f32_16x16x32_f16(bf0, qf[0][0], sa[0][ct], 0, 0, 0);
        sa[0][ct] = __builtin_amdgcn_mfma_f32_16x16x32_f16(bf1, qf[0][1], sa[0][ct], 0, 0, 0);
        sa[1][ct] = __builtin_amdgcn_mfma_f32_16x16x32_f16(bf0, qf[1][0], sa[1][ct], 0, 0, 0);
        sa[1][ct] = __builtin_amdgcn_mfma_f32_16x16x32_f16(bf1, qf[1][1], sa[1][ct], 0, 0, 0);
      }
    }
    // masking (fast path: tile fully unmasked). key = ct*16 + quad*4 + r
    if (__any((m0 == 0) || (m1 == 0))) {
#pragma unroll
      for (int ct = 0; ct < 8; ++ct)
#pragma unroll
        for (int r = 0; r < 4; ++r)
          if (Mb[key0 + ct * 16 + quad * 4 + r] == 0) {
            sa[0][ct][r] = -1e30f;
            sa[1][ct][r] = -1e30f;
          }
    }
    // online softmax per q-column (in-lane over 32 logits + 2 shuffles)
#pragma unroll
    for (int g = 0; g < 2; ++g) {
      float mx = sa[g][0][0];
#pragma unroll
      for (int ct = 0; ct < 8; ++ct)
#pragma unroll
        for (int r = 0; r < 4; ++r) mx = fmaxf(mx, sa[g][ct][r]);
      mx = fmaxf(mx, __shfl_xor(mx, 16));
      mx = fmaxf(mx, __shfl_xor(mx, 32));
      float mn = fmaxf(mi[g], mx);
      float alpha = __builtin_amdgcn_exp2f(mi[g] - mn);
      mi[g] = mn;
      float rs = 0.f;
#pragma unroll
      for (int ct = 0; ct < 8; ++ct)
#pragma unroll
        for (int r = 0; r < 4; ++r) {
          float p = __builtin_amdgcn_exp2f(sa[g][ct][r] - mn);
          sa[g][ct][r] = p;
          rs += p;
        }
      rs += __shfl_xor(rs, 16);
      rs += __shfl_xor(rs, 32);
      li[g] = li[g] * alpha + rs;
#pragma unroll
      for (int ct2 = 0; ct2 < 4; ++ct2) {
        o[g][ct2][0] *= alpha; o[g][ct2][1] *= alpha;
        o[g][ct2][2] *= alpha; o[g][ct2][3] *= alpha;
      }
    }
    // PV: O^T += mfma(A=V^T-frag, B=P^T-frag) over 8 key-chunks of 16.
    // P^T C-layout (key=quad*4+r) IS the 16x16x16 B-operand layout.
#pragma unroll
    for (int ct = 0; ct < 8; ++ct) {
      half4_t p0, p1;
#pragma unroll
      for (int r = 0; r < 4; ++r) {
        p0[r] = (_Float16)sa[0][ct][r];
        p1[r] = (_Float16)sa[1][ct][r];
      }
      int chunk = (2 * ct + (quad >> 1)) ^ l16;  // key-chunk swizzled by d&15
      int off = chunk * 8 + (quad & 1) * 4;
#pragma unroll
      for (int ct2 = 0; ct2 < 4; ++ct2) {
        int d = ct2 * 16 + l16;
        half4_t vf = *(half4_t*)&Vb[d * 128 + off];
        o[0][ct2] = __builtin_amdgcn_mfma_f32_16x16x16f16(vf, p0, o[0][ct2], 0, 0, 0);
        o[1][ct2] = __builtin_amdgcn_mfma_f32_16x16x16f16(vf, p1, o[1][ct2], 0, 0, 0);
      }
    }
  }
  // epilogue: normalize, store (B, S, H) fp16 — half4 stores (d contiguous)
#pragma unroll
  for (int g = 0; g < 2; ++g) {
    float inv = 1.0f / li[g];
    int row = qbase + w * 32 + g * 16 + l16;
#pragma unroll
    for (int ct2 = 0; ct2 < 4; ++ct2) {
      half4_t pk;
#pragma unroll
      for (int r = 0; r < 4; ++r) pk[r] = (_Float16)(o[g][ct2][r] * inv);
      int d = ct2 * 16 + quad * 4;
      *(half4_t*)&attn_out[((size_t)(b * S_ + row)) * H_ + h * HD_ + d] = pk;
    }
  }
}

// ---------------- Output GEMM: out = AO @ Wo^T (fp32 out) ------------------
// grid (16, 32) block 256: 128x64 tiles, BK=64, 16 K-iters (HALF the
// barriers of BK=32). Ring-3 of 24 KB K-tiles (72 KB LDS -> 2 blocks/CU,
// same occupancy as before), stage-ahead-2, counted vmcnt(6) (never 0 in
// main loop). Rows are 64 halfs (128 B) -> 8 slots of 16 B; reads use
// slot = chunk ^ (row&7) (conflict-free: lanes 0-7 hit 8 distinct bank
// quads, lanes 8-15 alias 2-way = free), staged via pre-swizzled source.
__global__ __launch_bounds__(256, 2) void out_gemm(
    const _Float16* __restrict__ A, const _Float16* __restrict__ W,
    float* __restrict__ out) {
  const int rbase = blockIdx.y * 128;
  const int cbase = blockIdx.x * 64;
  __shared__ _Float16 Ab[3][128 * 64];
  __shared__ _Float16 Bb[3][64 * 64];
  const int tid = threadIdx.x, lane = tid & 63, w = tid >> 6;
  const int quad = lane >> 4, l16 = lane & 15;

  floatx4 zero = {0.f, 0.f, 0.f, 0.f};
  floatx4 acc[2][4];
#pragma unroll
  for (int i = 0; i < 2; ++i)
#pragma unroll
    for (int j = 0; j < 4; ++j) acc[i][j] = zero;

  // staging: chunk c = tid + u*256 -> LDS row c>>3, slot c&7 (linear dest).
  // source col-chunk pre-swizzled: sslot = (tid&7) ^ ((tid>>3)&7); row
  // steps of 32 keep sslot invariant (32 == 0 mod 8).
  const int srow = tid >> 3;   // 0..31 (+u*32)
  const int pslot = tid & 7;
  const int sslot = pslot ^ (srow & 7);
  const _Float16* Ag = A + (size_t)(rbase + srow) * H_ + sslot * 8;
  const _Float16* Bg = W + (size_t)(cbase + srow) * H_ + sslot * 8;

  auto STAGE = [&](int s, int t) {
    const int k0 = t * 64;
    _Float16* ab = &Ab[s][tid * 8];
    _Float16* bb = &Bb[s][tid * 8];
#pragma unroll
    for (int u = 0; u < 4; ++u)
      async_copy16(ab + u * 2048, Ag + (size_t)(u * 32) * H_ + k0);
#pragma unroll
    for (int u = 0; u < 2; ++u)
      async_copy16(bb + u * 2048, Bg + (size_t)(u * 32) * H_ + k0);
  };

  const int rsw = l16 & 7;  // row&7 of fragment rows (base bits are 0 mod 8)
  auto COMPUTE = [&](int s) {
    const _Float16* Ap = &Ab[s][0];
    const _Float16* Bp = &Bb[s][0];
    half8 af[2][2], bf[4][2];
#pragma unroll
    for (int i = 0; i < 2; ++i)
#pragma unroll
      for (int hh = 0; hh < 2; ++hh)
        af[i][hh] = *(const half8*)&Ap[(w * 32 + i * 16 + l16) * 64 +
                                       (((hh * 4 + quad) ^ rsw) * 8)];
#pragma unroll
    for (int j = 0; j < 4; ++j)
#pragma unroll
      for (int hh = 0; hh < 2; ++hh)
        bf[j][hh] = *(const half8*)&Bp[(j * 16 + l16) * 64 +
                                       (((hh * 4 + quad) ^ rsw) * 8)];
    __builtin_amdgcn_s_setprio(1);
#pragma unroll
    for (int i = 0; i < 2; ++i)
#pragma unroll
      for (int j = 0; j < 4; ++j) {
        acc[i][j] = __builtin_amdgcn_mfma_f32_16x16x32_f16(af[i][0], bf[j][0],
                                                           acc[i][j], 0, 0, 0);
        acc[i][j] = __builtin_amdgcn_mfma_f32_16x16x32_f16(af[i][1], bf[j][1],
                                                           acc[i][j], 0, 0, 0);
      }
    __builtin_amdgcn_s_setprio(0);
  };

  STAGE(0, 0);
  STAGE(1, 1);
  int sc = 0;
  for (int t = 0; t < 14; ++t) {
    asm volatile("s_waitcnt vmcnt(6)" ::: "memory");
    __builtin_amdgcn_sched_barrier(0);
    __builtin_amdgcn_s_barrier();
    __builtin_amdgcn_sched_barrier(0);
    int ss = sc + 2; if (ss >= 3) ss -= 3;
    STAGE(ss, t + 2);
    COMPUTE(sc);
    sc = (sc == 2) ? 0 : sc + 1;
  }
  asm volatile("s_waitcnt vmcnt(6)" ::: "memory");
  __builtin_amdgcn_sched_barrier(0);
  __builtin_amdgcn_s_barrier();
  __builtin_amdgcn_sched_barrier(0);
  COMPUTE(sc);  // tile 14
  sc = (sc == 2) ? 0 : sc + 1;
  asm volatile("s_waitcnt vmcnt(0)" ::: "memory");
  __builtin_amdgcn_sched_barrier(0);
  __builtin_amdgcn_s_barrier();
  __builtin_amdgcn_sched_barrier(0);
  COMPUTE(sc);  // tile 15

#pragma unroll
  for (int i = 0; i < 2; ++i) {
    int r0 = rbase + w * 32 + i * 16 + quad * 4;
#pragma unroll
    for (int j = 0; j < 4; ++j) {
      int col = cbase + j * 16 + l16;
#pragma unroll
      for (int r = 0; r < 4; ++r)
        out[(size_t)(r0 + r) * H_ + col] = acc[i][j][r];
    }
  }
}

extern "C" void kernel_launch(void* const* d_in, const int* in_sizes, int n_in,
                              void* d_out, int out_size, void* d_ws,
                              size_t ws_size, hipStream_t stream) {
  const float* hs = (const float*)d_in[0];
  const int* mask = (const int*)d_in[1];
  const float* Wq = (const float*)d_in[2];
  const float* Wk = (const float*)d_in[3];
  const float* Wv = (const float*)d_in[4];
  const float* Wo = (const float*)d_in[5];
  float* out = (float*)d_out;

  _Float16* p = (_Float16*)d_ws;
  _Float16* hs_h = p; p += (size_t)BS_ * H_;
  _Float16* w_h = p;  p += (size_t)4 * H_ * H_;
  _Float16* q_h = p;  p += (size_t)BS_ * H_;
  _Float16* k_h = p;  p += (size_t)BS_ * H_;
  _Float16* v_t = p;  p += (size_t)BS_ * H_;
  _Float16* ao_h = p; p += (size_t)BS_ * H_;

  cvt_all<<<8192, 256, 0, stream>>>(hs, Wq, Wk, Wv, Wo, hs_h, w_h);
  qkv_gemm<<<dim3(8, 32, 3), 256, 0, stream>>>(hs_h, w_h, q_h, k_h, v_t);
  flash_attn<<<dim3(16, 32), 256, 0, stream>>>(q_h, k_h, v_t, mask, ao_h);
  out_gemm<<<dim3(16, 32), 256, 0, stream>>>(ao_h, w_h + (size_t)3 * H_ * H_, out);
}